// Round 8
// baseline (142.180 us; speedup 1.0000x reference)
//
#include <hip/hip_runtime.h>
#include <math.h>

#define BB 2
#define TT 2048
#define DD 1024
#define HH 16
#define BT (BB*TT)   // 4096
#define VD 1280      // qkv fused output width

typedef __attribute__((ext_vector_type(4))) _Float16 f16x4;
typedef __attribute__((ext_vector_type(8))) _Float16 f16x8;
typedef __attribute__((ext_vector_type(4))) float f32x4;

__device__ __forceinline__ void gload16(const void* g, void* l) {
    __builtin_amdgcn_global_load_lds((const __attribute__((address_space(1))) void*)g,
                                     (__attribute__((address_space(3))) void*)l, 16, 0, 0);
}

// ---------------- fp32 -> f16 conversion / packing -------------------------
__global__ __launch_bounds__(256) void convert_kernel(
    const float* __restrict__ x,  const float* __restrict__ W1q,
    const float* __restrict__ W2q, const float* __restrict__ W1k,
    const float* __restrict__ W2k, const float* __restrict__ Wv,
    const float* __restrict__ Wout, const float* __restrict__ bv,
    _Float16* __restrict__ xb, _Float16* __restrict__ Wqkvb,
    _Float16* __restrict__ Woutb, float* __restrict__ biasqkv) {
    int c = blockIdx.x * 256 + threadIdx.x;   // chunk of 8 elements
    if (c < 819200) {
        const float* src; _Float16* dst; int off;
        if      (c < 524288) { src = x;    dst = xb;              off = c; }
        else if (c < 532480) { src = W1q;  dst = Wqkvb;           off = c - 524288; }
        else if (c < 540672) { src = W2q;  dst = Wqkvb + 65536;   off = c - 532480; }
        else if (c < 548864) { src = W1k;  dst = Wqkvb + 131072;  off = c - 540672; }
        else if (c < 557056) { src = W2k;  dst = Wqkvb + 196608;  off = c - 548864; }
        else if (c < 688128) { src = Wv;   dst = Wqkvb + 262144;  off = c - 557056; }
        else                 { src = Wout; dst = Woutb;           off = c - 688128; }
        float4 v0 = *(const float4*)(src + (size_t)off * 8);
        float4 v1 = *(const float4*)(src + (size_t)off * 8 + 4);
        f16x8 h;
        h[0] = (_Float16)v0.x; h[1] = (_Float16)v0.y; h[2] = (_Float16)v0.z; h[3] = (_Float16)v0.w;
        h[4] = (_Float16)v1.x; h[5] = (_Float16)v1.y; h[6] = (_Float16)v1.z; h[7] = (_Float16)v1.w;
        *(f16x8*)(dst + (size_t)off * 8) = h;
    } else if (c < 819360) {
        int col0 = (c - 819200) * 8;
        #pragma unroll
        for (int i = 0; i < 8; ++i) {
            int col = col0 + i;
            biasqkv[col] = (col < 256) ? 0.f : bv[col - 256];
        }
    }
}

// ---------------- f16 MFMA GEMM: C[M,N] = A[M,K] @ W[N,K]^T + bias ---------
__global__ __launch_bounds__(256) void gemm_f16_mfma(
    const _Float16* __restrict__ A, const _Float16* __restrict__ W,
    const float* __restrict__ bias, float* __restrict__ C, int N, int K) {
    __shared__ __attribute__((aligned(16))) _Float16 As[128 * 32];
    __shared__ __attribute__((aligned(16))) _Float16 Ws[128 * 32];
    const int tid = threadIdx.x;
    const int w = tid >> 6, lane = tid & 63;
    const int la = lane >> 4, lb = lane & 15;
    const int bm = blockIdx.x * 128, bn = blockIdx.y * 128;
    const int wr = w >> 1, wc = w & 1;

    const int c0 = tid, c1 = tid + 256;
    const int r0 = c0 >> 2, kg0 = (c0 & 3) ^ ((r0 >> 1) & 3);
    const int r1 = c1 >> 2, kg1 = (c1 & 3) ^ ((r1 >> 1) & 3);
    const _Float16* Ag0 = A + (size_t)(bm + r0) * K + kg0 * 8;
    const _Float16* Ag1 = A + (size_t)(bm + r1) * K + kg1 * 8;
    const _Float16* Wg0 = W + (size_t)(bn + r0) * K + kg0 * 8;
    const _Float16* Wg1 = W + (size_t)(bn + r1) * K + kg1 * 8;
    _Float16* Al0 = &As[(w * 64) * 8];
    _Float16* Al1 = &As[(256 + w * 64) * 8];
    _Float16* Wl0 = &Ws[(w * 64) * 8];
    _Float16* Wl1 = &Ws[(256 + w * 64) * 8];

    f32x4 acc[4][4] = {};

    int aoff[4], boff[4];
    #pragma unroll
    for (int t = 0; t < 4; ++t) {
        int ra = wr * 64 + t * 16 + lb;
        aoff[t] = ra * 32 + (la ^ ((ra >> 1) & 3)) * 8;
        int rb = wc * 64 + t * 16 + lb;
        boff[t] = rb * 32 + (la ^ ((rb >> 1) & 3)) * 8;
    }

    for (int k0 = 0; k0 < K; k0 += 32) {
        gload16(Ag0 + k0, Al0);
        gload16(Ag1 + k0, Al1);
        gload16(Wg0 + k0, Wl0);
        gload16(Wg1 + k0, Wl1);
        __syncthreads();
        f16x8 af[4], bf[4];
        #pragma unroll
        for (int t = 0; t < 4; ++t) af[t] = *(const f16x8*)&As[aoff[t]];
        #pragma unroll
        for (int t = 0; t < 4; ++t) bf[t] = *(const f16x8*)&Ws[boff[t]];
        #pragma unroll
        for (int mt = 0; mt < 4; ++mt)
            #pragma unroll
            for (int nt = 0; nt < 4; ++nt)
                acc[mt][nt] = __builtin_amdgcn_mfma_f32_16x16x32_f16(
                    af[mt], bf[nt], acc[mt][nt], 0, 0, 0);
        __syncthreads();
    }

    #pragma unroll
    for (int nt = 0; nt < 4; ++nt) {
        int col = bn + wc * 64 + nt * 16 + lb;
        float bval = bias ? bias[col] : 0.f;
        #pragma unroll
        for (int mt = 0; mt < 4; ++mt) {
            int row = bm + wr * 64 + mt * 16 + la * 4;
            #pragma unroll
            for (int i = 0; i < 4; ++i)
                C[(size_t)(row + i) * N + col] = acc[mt][nt][i] + bval;
        }
    }
}

// ---------------- exterior (Plucker) --------------------------------------
// Lqh: [bh][t][16] f16 (c 6..15 zero).
// JKf: MFMA A-fragment order [bh][tile(32)][n(4)][lane(64)][4] f16 so flash
//      reads are lane-linear b64 (conflict-free). J6, 6^-0.5, log2(e) folded.
__device__ __forceinline__ void ext6(const float* a, const float* b, float* L) {
    L[0] = a[0]*b[1] - a[1]*b[0];
    L[1] = a[0]*b[2] - a[2]*b[0];
    L[2] = a[0]*b[3] - a[3]*b[0];
    L[3] = a[1]*b[2] - a[2]*b[1];
    L[4] = a[1]*b[3] - a[3]*b[1];
    L[5] = a[2]*b[3] - a[3]*b[2];
}

__global__ __launch_bounds__(256) void exterior_kernel(const float* __restrict__ Cqkv,
                                                       _Float16* __restrict__ Lqh,
                                                       _Float16* __restrict__ JKf) {
    int idx = blockIdx.x * 256 + threadIdx.x;     // over BT*HH
    if (idx >= BT * HH) return;
    int bt = idx >> 4, h = idx & 15;
    int b = bt >> 11, t = bt & (TT - 1);
    int bh = b * HH + h;
    const float* row = Cqkv + (size_t)bt * VD + h * 4;
    const _Float16 Z = (_Float16)0.f;
    float a[4], bb[4], L[6];
    #pragma unroll
    for (int i = 0; i < 4; ++i) { a[i] = row[i]; bb[i] = row[64 + i]; }
    ext6(a, bb, L);
    float s = 0.f;
    #pragma unroll
    for (int c = 0; c < 6; ++c) s += L[c] * L[c];
    float inv = 1.0f / fmaxf(sqrtf(s), 1e-12f);
    size_t qbase = ((size_t)bh * TT + t) * 16;
    f16x8 lq8 = {(_Float16)(L[0]*inv), (_Float16)(L[1]*inv), (_Float16)(L[2]*inv),
                 (_Float16)(L[3]*inv), (_Float16)(L[4]*inv), (_Float16)(L[5]*inv), Z, Z};
    f16x8 zero8 = {Z, Z, Z, Z, Z, Z, Z, Z};
    *(f16x8*)(Lqh + qbase) = lq8;
    *(f16x8*)(Lqh + qbase + 8) = zero8;

    #pragma unroll
    for (int i = 0; i < 4; ++i) { a[i] = row[128 + i]; bb[i] = row[192 + i]; }
    ext6(a, bb, L);
    s = 0.f;
    #pragma unroll
    for (int c = 0; c < 6; ++c) s += L[c] * L[c];
    const float SCALE = (float)(0.40824829046386307 * 1.4426950408889634); // 6^-0.5 * log2(e)
    inv = SCALE / fmaxf(sqrtf(s), 1e-12f);
    // fragment position: tile = t>>6, n = (t&63)>>4, lbt = t&15; granule la
    int tile = t >> 6, rr = t & 63, n = rr >> 4, lbt = rr & 15;
    size_t base = (((size_t)bh * 32 + tile) * 1024) + n * 256 + lbt * 4;
    f16x4 g0 = {(_Float16)( L[5]*inv), (_Float16)(-L[4]*inv),
                (_Float16)( L[3]*inv), (_Float16)( L[2]*inv)};
    f16x4 g1 = {(_Float16)(-L[1]*inv), (_Float16)( L[0]*inv), Z, Z};
    f16x4 z4 = {Z, Z, Z, Z};
    *(f16x4*)&JKf[base]       = g0;   // la=0: c0..3
    *(f16x4*)&JKf[base + 64]  = g1;   // la=1: c4..7
    *(f16x4*)&JKf[base + 128] = z4;   // la=2
    *(f16x4*)&JKf[base + 192] = z4;   // la=3
}

// ---------------- V transpose into PV A-fragment order ---------------------
// Vf: [bh][tile(32)][m*4+n(16)][lane(64)][4] f16 where lane=la*16+lb holds
//     V[t = tile*64 + n*16 + la*4 + j][d = m*16 + lb].
__global__ __launch_bounds__(256) void vtrans_kernel(const float* __restrict__ Cqkv,
                                                     _Float16* __restrict__ Vf) {
    __shared__ float ls[64][65];
    const int bh = blockIdx.y, b = bh >> 4, h = bh & 15;
    const int tile = blockIdx.x;
    const int t0 = tile * 64;
    const int tid = threadIdx.x;
    const int tr = tid >> 2, dg = (tid & 3) * 16;
    const float* src = Cqkv + (size_t)(b * TT + t0 + tr) * VD + 256 + h * 64 + dg;
    #pragma unroll
    for (int j = 0; j < 4; ++j) {
        float4 v = *(const float4*)(src + j * 4);
        ls[tr][dg + j*4 + 0] = v.x;
        ls[tr][dg + j*4 + 1] = v.y;
        ls[tr][dg + j*4 + 2] = v.z;
        ls[tr][dg + j*4 + 3] = v.w;
    }
    __syncthreads();
    _Float16* dst = Vf + ((size_t)bh * 32 + tile) * 4096;
    #pragma unroll
    for (int k = 0; k < 4; ++k) {
        int g = k * 256 + tid;                 // granule id 0..1023
        int mn = g >> 6, lane = g & 63;
        int m = mn >> 2, n = mn & 3;
        int la = lane >> 4, lb = lane & 15;
        int d = m * 16 + lb, tt = n * 16 + la * 4;
        f16x4 o = { (_Float16)ls[tt][d], (_Float16)ls[tt+1][d],
                    (_Float16)ls[tt+2][d], (_Float16)ls[tt+3][d] };
        *(f16x4*)&dst[(size_t)g * 4] = o;
    }
}

// ---------------- MFMA flash attention v4 ----------------------------------
// grid (TT/64, B*H); 4 waves x 16 q. NO barriers: each wave stages its own
// 10KB LDS region (JK 2KB + V 8KB, both pre-arranged in fragment order ->
// lane-linear gload16 staging AND lane-linear conflict-free b64 reads).
// p = exp2(s') directly (scores bounded by 6^-0.5, no online max).
__global__ __launch_bounds__(256, 4) void flash_mfma_kernel(
    const _Float16* __restrict__ Lqh, const _Float16* __restrict__ JKf,
    const _Float16* __restrict__ Vf, _Float16* __restrict__ O) {
    const int qb = (int)gridDim.x - 1 - (int)blockIdx.x;  // heavy blocks first
    const int bh = blockIdx.y;
    const int b = bh >> 4, h = bh & 15;
    const int tid = threadIdx.x;
    const int w = tid >> 6, lane = tid & 63;
    const int la = lane >> 4, lb = lane & 15;
    const int qw = qb * 64 + w * 16;

    __shared__ __attribute__((aligned(16))) _Float16 sm[4][5120];  // 40 KB
    _Float16* jk = sm[w];            // 1024 f16
    _Float16* vt = sm[w] + 1024;     // 4096 f16

    // B-frag: blq[j] = Lq[q=qw+lb][k=la*4+j]; k>=6 stored zero
    f16x4 blq = *(const f16x4*)(Lqh + ((size_t)bh * TT + qw + lb) * 16 + la * 4);

    f32x4 acc[4] = {};
    float lsum = 0.f;

    const _Float16* jsrc = JKf + (size_t)bh * (TT * 16) + lane * 8;
    const _Float16* vsrc = Vf + (size_t)bh * (TT * 64) + lane * 8;

    for (int t = 0; t <= qb; ++t) {
        // fence: prior ds_reads must retire before overwriting the buffer
        asm volatile("s_waitcnt lgkmcnt(0)" ::: "memory");
        const _Float16* jp = jsrc + (size_t)t * 1024;
        const _Float16* vp = vsrc + (size_t)t * 4096;
        gload16(jp, jk);
        gload16(jp + 512, jk + 512);
        #pragma unroll
        for (int j = 0; j < 8; ++j)
            gload16(vp + j * 512, vt + j * 512);
        asm volatile("s_waitcnt vmcnt(0)" ::: "memory");

        const int kt = t * 64;
        #pragma unroll
        for (int n = 0; n < 4; ++n) {
            const int kbase = kt + n * 16;
            if (kbase > qw + 15) break;                 // wave-uniform
            f16x4 ajk = *(const f16x4*)&jk[n * 256 + lane * 4];
            f32x4 st = __builtin_amdgcn_mfma_f32_16x16x16f16(
                ajk, blq, (f32x4){0.f, 0.f, 0.f, 0.f}, 0, 0, 0);
            const bool needm = (kbase + 15 > qw);
            f16x4 pt;
            #pragma unroll
            for (int i = 0; i < 4; ++i) {
                float p = exp2f(st[i]);
                if (needm) {
                    int key = kbase + la * 4 + i;
                    p = (key <= qw + lb) ? p : 0.f;
                }
                lsum += p;
                pt[i] = (_Float16)p;
            }
            #pragma unroll
            for (int m = 0; m < 4; ++m) {
                f16x4 av = *(const f16x4*)&vt[(m * 4 + n) * 256 + lane * 4];
                acc[m] = __builtin_amdgcn_mfma_f32_16x16x16f16(av, pt, acc[m], 0, 0, 0);
            }
        }
    }

    // reduce lsum across the 4 la-groups holding the same q column
    lsum += __shfl_xor(lsum, 16);
    lsum += __shfl_xor(lsum, 32);
    const float inv = 1.f / lsum;
    const int q = qw + lb;
    #pragma unroll
    for (int m = 0; m < 4; ++m) {
        f16x4 o = { (_Float16)(acc[m][0] * inv), (_Float16)(acc[m][1] * inv),
                    (_Float16)(acc[m][2] * inv), (_Float16)(acc[m][3] * inv) };
        *(f16x4*)&O[(size_t)(b * TT + q) * DD + h * 64 + m * 16 + la * 4] = o;
    }
}

extern "C" void kernel_launch(void* const* d_in, const int* in_sizes, int n_in,
                              void* d_out, int out_size, void* d_ws, size_t ws_size,
                              hipStream_t stream) {
    const float* x    = (const float*)d_in[0];
    const float* W1q  = (const float*)d_in[1];
    const float* W2q  = (const float*)d_in[2];
    const float* W1k  = (const float*)d_in[3];
    const float* W2k  = (const float*)d_in[4];
    const float* Wv   = (const float*)d_in[5];
    const float* bv   = (const float*)d_in[6];
    const float* Wout = (const float*)d_in[7];
    const float* bout = (const float*)d_in[8];
    float* out = (float*)d_out;

    char* wsb = (char*)d_ws;
    _Float16* xb      = (_Float16*)(wsb);                  //  8,388,608
    _Float16* AObf    = (_Float16*)(wsb);                  //  aliases xb (dead after qkv GEMM)
    _Float16* Wqkvb   = (_Float16*)(wsb + 8388608);        //  2,621,440
    _Float16* Woutb   = (_Float16*)(wsb + 11010048);       //  2,097,152
    float*    biasqkv = (float*)   (wsb + 13107200);       //      5,120
    float*    Cqkv    = (float*)   (wsb + 13112320);       // 20,971,520
    _Float16* Lqh     = (_Float16*)(wsb + 34083840);       //  2,097,152
    _Float16* JKf     = (_Float16*)(wsb + 36180992);       //  2,097,152
    _Float16* Vf      = (_Float16*)(wsb + 38278144);       //  8,388,608  (end ~44.5 MB)

    // 1. fp32 -> f16 pack
    convert_kernel<<<dim3(3201), 256, 0, stream>>>(
        x, W1q, W2q, W1k, W2k, Wv, Wout, bv, xb, Wqkvb, Woutb, biasqkv);
    // 2. fused qkv projection: Cqkv = xb @ Wqkvb^T + biasqkv   [4096,1280]
    gemm_f16_mfma<<<dim3(BT / 128, VD / 128), 256, 0, stream>>>(
        xb, Wqkvb, biasqkv, Cqkv, VD, DD);
    // 3. Plucker lines -> Lqh + JKf (fragment order)
    exterior_kernel<<<dim3(BT * HH / 256), 256, 0, stream>>>(Cqkv, Lqh, JKf);
    // 4. V -> PV-fragment order f16
    vtrans_kernel<<<dim3(TT / 64, BB * HH), 256, 0, stream>>>(Cqkv, Vf);
    // 5. causal flash attention (barrier-free, per-wave staging)
    flash_mfma_kernel<<<dim3(TT / 64, BB * HH), 256, 0, stream>>>(Lqh, JKf, Vf, AObf);
    // 6. output projection
    gemm_f16_mfma<<<dim3(BT / 128, DD / 128), 256, 0, stream>>>(
        AObf, Woutb, bout, out, DD, DD);
}

// Round 9
// 141.903 us; speedup vs baseline: 1.0019x; 1.0019x over previous
//
#include <hip/hip_runtime.h>
#include <math.h>

#define BB 2
#define TT 2048
#define DD 1024
#define HH 16
#define BT (BB*TT)   // 4096
#define VD 1280      // qkv fused output width

typedef __attribute__((ext_vector_type(4))) _Float16 f16x4;
typedef __attribute__((ext_vector_type(8))) _Float16 f16x8;
typedef __attribute__((ext_vector_type(4))) float f32x4;

__device__ __forceinline__ void gload16(const void* g, void* l) {
    __builtin_amdgcn_global_load_lds((const __attribute__((address_space(1))) void*)g,
                                     (__attribute__((address_space(3))) void*)l, 16, 0, 0);
}

// ---------------- fp32 -> f16 conversion / packing -------------------------
__global__ __launch_bounds__(256) void convert_kernel(
    const float* __restrict__ x,  const float* __restrict__ W1q,
    const float* __restrict__ W2q, const float* __restrict__ W1k,
    const float* __restrict__ W2k, const float* __restrict__ Wv,
    const float* __restrict__ Wout, const float* __restrict__ bv,
    _Float16* __restrict__ xb, _Float16* __restrict__ Wqkvb,
    _Float16* __restrict__ Woutb, float* __restrict__ biasqkv) {
    int c = blockIdx.x * 256 + threadIdx.x;   // chunk of 8 elements
    if (c < 819200) {
        const float* src; _Float16* dst; int off;
        if      (c < 524288) { src = x;    dst = xb;              off = c; }
        else if (c < 532480) { src = W1q;  dst = Wqkvb;           off = c - 524288; }
        else if (c < 540672) { src = W2q;  dst = Wqkvb + 65536;   off = c - 532480; }
        else if (c < 548864) { src = W1k;  dst = Wqkvb + 131072;  off = c - 540672; }
        else if (c < 557056) { src = W2k;  dst = Wqkvb + 196608;  off = c - 548864; }
        else if (c < 688128) { src = Wv;   dst = Wqkvb + 262144;  off = c - 557056; }
        else                 { src = Wout; dst = Woutb;           off = c - 688128; }
        float4 v0 = *(const float4*)(src + (size_t)off * 8);
        float4 v1 = *(const float4*)(src + (size_t)off * 8 + 4);
        f16x8 h;
        h[0] = (_Float16)v0.x; h[1] = (_Float16)v0.y; h[2] = (_Float16)v0.z; h[3] = (_Float16)v0.w;
        h[4] = (_Float16)v1.x; h[5] = (_Float16)v1.y; h[6] = (_Float16)v1.z; h[7] = (_Float16)v1.w;
        *(f16x8*)(dst + (size_t)off * 8) = h;
    } else if (c < 819360) {
        int col0 = (c - 819200) * 8;
        #pragma unroll
        for (int i = 0; i < 8; ++i) {
            int col = col0 + i;
            biasqkv[col] = (col < 256) ? 0.f : bv[col - 256];
        }
    }
}

// ---------------- f16 MFMA GEMM: C[M,N] = A[M,K] @ W[N,K]^T + bias ---------
__global__ __launch_bounds__(256) void gemm_f16_mfma(
    const _Float16* __restrict__ A, const _Float16* __restrict__ W,
    const float* __restrict__ bias, float* __restrict__ C, int N, int K) {
    __shared__ __attribute__((aligned(16))) _Float16 As[128 * 32];
    __shared__ __attribute__((aligned(16))) _Float16 Ws[128 * 32];
    const int tid = threadIdx.x;
    const int w = tid >> 6, lane = tid & 63;
    const int la = lane >> 4, lb = lane & 15;
    const int bm = blockIdx.x * 128, bn = blockIdx.y * 128;
    const int wr = w >> 1, wc = w & 1;

    const int c0 = tid, c1 = tid + 256;
    const int r0 = c0 >> 2, kg0 = (c0 & 3) ^ ((r0 >> 1) & 3);
    const int r1 = c1 >> 2, kg1 = (c1 & 3) ^ ((r1 >> 1) & 3);
    const _Float16* Ag0 = A + (size_t)(bm + r0) * K + kg0 * 8;
    const _Float16* Ag1 = A + (size_t)(bm + r1) * K + kg1 * 8;
    const _Float16* Wg0 = W + (size_t)(bn + r0) * K + kg0 * 8;
    const _Float16* Wg1 = W + (size_t)(bn + r1) * K + kg1 * 8;
    _Float16* Al0 = &As[(w * 64) * 8];
    _Float16* Al1 = &As[(256 + w * 64) * 8];
    _Float16* Wl0 = &Ws[(w * 64) * 8];
    _Float16* Wl1 = &Ws[(256 + w * 64) * 8];

    f32x4 acc[4][4] = {};

    int aoff[4], boff[4];
    #pragma unroll
    for (int t = 0; t < 4; ++t) {
        int ra = wr * 64 + t * 16 + lb;
        aoff[t] = ra * 32 + (la ^ ((ra >> 1) & 3)) * 8;
        int rb = wc * 64 + t * 16 + lb;
        boff[t] = rb * 32 + (la ^ ((rb >> 1) & 3)) * 8;
    }

    for (int k0 = 0; k0 < K; k0 += 32) {
        gload16(Ag0 + k0, Al0);
        gload16(Ag1 + k0, Al1);
        gload16(Wg0 + k0, Wl0);
        gload16(Wg1 + k0, Wl1);
        __syncthreads();
        f16x8 af[4], bf[4];
        #pragma unroll
        for (int t = 0; t < 4; ++t) af[t] = *(const f16x8*)&As[aoff[t]];
        #pragma unroll
        for (int t = 0; t < 4; ++t) bf[t] = *(const f16x8*)&Ws[boff[t]];
        #pragma unroll
        for (int mt = 0; mt < 4; ++mt)
            #pragma unroll
            for (int nt = 0; nt < 4; ++nt)
                acc[mt][nt] = __builtin_amdgcn_mfma_f32_16x16x32_f16(
                    af[mt], bf[nt], acc[mt][nt], 0, 0, 0);
        __syncthreads();
    }

    #pragma unroll
    for (int nt = 0; nt < 4; ++nt) {
        int col = bn + wc * 64 + nt * 16 + lb;
        float bval = bias ? bias[col] : 0.f;
        #pragma unroll
        for (int mt = 0; mt < 4; ++mt) {
            int row = bm + wr * 64 + mt * 16 + la * 4;
            #pragma unroll
            for (int i = 0; i < 4; ++i)
                C[(size_t)(row + i) * N + col] = acc[mt][nt][i] + bval;
        }
    }
}

// ---------------- exterior (Plucker) --------------------------------------
// Lqh: [bh][t][16] f16 (c 6..15 zero).
// JKf: MFMA A-fragment order [bh][tile(32)][n(4)][lane(64)][4] f16 so flash
//      reads are lane-linear b64 (conflict-free). J6, 6^-0.5, log2(e) folded.
__device__ __forceinline__ void ext6(const float* a, const float* b, float* L) {
    L[0] = a[0]*b[1] - a[1]*b[0];
    L[1] = a[0]*b[2] - a[2]*b[0];
    L[2] = a[0]*b[3] - a[3]*b[0];
    L[3] = a[1]*b[2] - a[2]*b[1];
    L[4] = a[1]*b[3] - a[3]*b[1];
    L[5] = a[2]*b[3] - a[3]*b[2];
}

__global__ __launch_bounds__(256) void exterior_kernel(const float* __restrict__ Cqkv,
                                                       _Float16* __restrict__ Lqh,
                                                       _Float16* __restrict__ JKf) {
    int idx = blockIdx.x * 256 + threadIdx.x;     // over BT*HH
    if (idx >= BT * HH) return;
    int bt = idx >> 4, h = idx & 15;
    int b = bt >> 11, t = bt & (TT - 1);
    int bh = b * HH + h;
    const float* row = Cqkv + (size_t)bt * VD + h * 4;
    const _Float16 Z = (_Float16)0.f;
    float a[4], bb[4], L[6];
    #pragma unroll
    for (int i = 0; i < 4; ++i) { a[i] = row[i]; bb[i] = row[64 + i]; }
    ext6(a, bb, L);
    float s = 0.f;
    #pragma unroll
    for (int c = 0; c < 6; ++c) s += L[c] * L[c];
    float inv = 1.0f / fmaxf(sqrtf(s), 1e-12f);
    size_t qbase = ((size_t)bh * TT + t) * 16;
    f16x8 lq8 = {(_Float16)(L[0]*inv), (_Float16)(L[1]*inv), (_Float16)(L[2]*inv),
                 (_Float16)(L[3]*inv), (_Float16)(L[4]*inv), (_Float16)(L[5]*inv), Z, Z};
    f16x8 zero8 = {Z, Z, Z, Z, Z, Z, Z, Z};
    *(f16x8*)(Lqh + qbase) = lq8;
    *(f16x8*)(Lqh + qbase + 8) = zero8;

    #pragma unroll
    for (int i = 0; i < 4; ++i) { a[i] = row[128 + i]; bb[i] = row[192 + i]; }
    ext6(a, bb, L);
    s = 0.f;
    #pragma unroll
    for (int c = 0; c < 6; ++c) s += L[c] * L[c];
    const float SCALE = (float)(0.40824829046386307 * 1.4426950408889634); // 6^-0.5 * log2(e)
    inv = SCALE / fmaxf(sqrtf(s), 1e-12f);
    // fragment position: tile = t>>6, n = (t&63)>>4, lbt = t&15; granule la
    int tile = t >> 6, rr = t & 63, n = rr >> 4, lbt = rr & 15;
    size_t base = (((size_t)bh * 32 + tile) * 1024) + n * 256 + lbt * 4;
    f16x4 g0 = {(_Float16)( L[5]*inv), (_Float16)(-L[4]*inv),
                (_Float16)( L[3]*inv), (_Float16)( L[2]*inv)};
    f16x4 g1 = {(_Float16)(-L[1]*inv), (_Float16)( L[0]*inv), Z, Z};
    f16x4 z4 = {Z, Z, Z, Z};
    *(f16x4*)&JKf[base]       = g0;   // la=0: c0..3
    *(f16x4*)&JKf[base + 64]  = g1;   // la=1: c4..7
    *(f16x4*)&JKf[base + 128] = z4;   // la=2
    *(f16x4*)&JKf[base + 192] = z4;   // la=3
}

// ---------------- V transpose into PV A-fragment order ---------------------
// Vf: [bh][tile(32)][m*4+n(16)][lane(64)][4] f16 where lane=la*16+lb holds
//     V[t = tile*64 + n*16 + la*4 + j][d = m*16 + lb].
__global__ __launch_bounds__(256) void vtrans_kernel(const float* __restrict__ Cqkv,
                                                     _Float16* __restrict__ Vf) {
    __shared__ float ls[64][65];
    const int bh = blockIdx.y, b = bh >> 4, h = bh & 15;
    const int tile = blockIdx.x;
    const int t0 = tile * 64;
    const int tid = threadIdx.x;
    const int tr = tid >> 2, dg = (tid & 3) * 16;
    const float* src = Cqkv + (size_t)(b * TT + t0 + tr) * VD + 256 + h * 64 + dg;
    #pragma unroll
    for (int j = 0; j < 4; ++j) {
        float4 v = *(const float4*)(src + j * 4);
        ls[tr][dg + j*4 + 0] = v.x;
        ls[tr][dg + j*4 + 1] = v.y;
        ls[tr][dg + j*4 + 2] = v.z;
        ls[tr][dg + j*4 + 3] = v.w;
    }
    __syncthreads();
    _Float16* dst = Vf + ((size_t)bh * 32 + tile) * 4096;
    #pragma unroll
    for (int k = 0; k < 4; ++k) {
        int g = k * 256 + tid;                 // granule id 0..1023
        int mn = g >> 6, lane = g & 63;
        int m = mn >> 2, n = mn & 3;
        int la = lane >> 4, lb = lane & 15;
        int d = m * 16 + lb, tt = n * 16 + la * 4;
        f16x4 o = { (_Float16)ls[tt][d], (_Float16)ls[tt+1][d],
                    (_Float16)ls[tt+2][d], (_Float16)ls[tt+3][d] };
        *(f16x4*)&dst[(size_t)g * 4] = o;
    }
}

// ---------------- MFMA flash attention v4 ----------------------------------
// grid (TT/64, B*H); 4 waves x 16 q. NO barriers: each wave stages its own
// 10KB LDS region (JK 2KB + V 8KB, both pre-arranged in fragment order ->
// lane-linear gload16 staging AND lane-linear conflict-free b64 reads).
// p = exp2(s') directly (scores bounded by 6^-0.5, no online max).
__global__ __launch_bounds__(256, 4) void flash_mfma_kernel(
    const _Float16* __restrict__ Lqh, const _Float16* __restrict__ JKf,
    const _Float16* __restrict__ Vf, _Float16* __restrict__ O) {
    const int qb = (int)gridDim.x - 1 - (int)blockIdx.x;  // heavy blocks first
    const int bh = blockIdx.y;
    const int b = bh >> 4, h = bh & 15;
    const int tid = threadIdx.x;
    const int w = tid >> 6, lane = tid & 63;
    const int la = lane >> 4, lb = lane & 15;
    const int qw = qb * 64 + w * 16;

    __shared__ __attribute__((aligned(16))) _Float16 sm[4][5120];  // 40 KB
    _Float16* jk = sm[w];            // 1024 f16
    _Float16* vt = sm[w] + 1024;     // 4096 f16

    // B-frag: blq[j] = Lq[q=qw+lb][k=la*4+j]; k>=6 stored zero
    f16x4 blq = *(const f16x4*)(Lqh + ((size_t)bh * TT + qw + lb) * 16 + la * 4);

    f32x4 acc[4] = {};
    float lsum = 0.f;

    const _Float16* jsrc = JKf + (size_t)bh * (TT * 16) + lane * 8;
    const _Float16* vsrc = Vf + (size_t)bh * (TT * 64) + lane * 8;

    for (int t = 0; t <= qb; ++t) {
        // fence: prior ds_reads must retire before overwriting the buffer
        asm volatile("s_waitcnt lgkmcnt(0)" ::: "memory");
        const _Float16* jp = jsrc + (size_t)t * 1024;
        const _Float16* vp = vsrc + (size_t)t * 4096;
        gload16(jp, jk);
        gload16(jp + 512, jk + 512);
        #pragma unroll
        for (int j = 0; j < 8; ++j)
            gload16(vp + j * 512, vt + j * 512);
        asm volatile("s_waitcnt vmcnt(0)" ::: "memory");

        const int kt = t * 64;
        #pragma unroll
        for (int n = 0; n < 4; ++n) {
            const int kbase = kt + n * 16;
            if (kbase > qw + 15) break;                 // wave-uniform
            f16x4 ajk = *(const f16x4*)&jk[n * 256 + lane * 4];
            f32x4 st = __builtin_amdgcn_mfma_f32_16x16x16f16(
                ajk, blq, (f32x4){0.f, 0.f, 0.f, 0.f}, 0, 0, 0);
            const bool needm = (kbase + 15 > qw);
            f16x4 pt;
            #pragma unroll
            for (int i = 0; i < 4; ++i) {
                float p = exp2f(st[i]);
                if (needm) {
                    int key = kbase + la * 4 + i;
                    p = (key <= qw + lb) ? p : 0.f;
                }
                lsum += p;
                pt[i] = (_Float16)p;
            }
            #pragma unroll
            for (int m = 0; m < 4; ++m) {
                f16x4 av = *(const f16x4*)&vt[(m * 4 + n) * 256 + lane * 4];
                acc[m] = __builtin_amdgcn_mfma_f32_16x16x16f16(av, pt, acc[m], 0, 0, 0);
            }
        }
    }

    // reduce lsum across the 4 la-groups holding the same q column
    lsum += __shfl_xor(lsum, 16);
    lsum += __shfl_xor(lsum, 32);
    const float inv = 1.f / lsum;
    const int q = qw + lb;
    #pragma unroll
    for (int m = 0; m < 4; ++m) {
        f16x4 o = { (_Float16)(acc[m][0] * inv), (_Float16)(acc[m][1] * inv),
                    (_Float16)(acc[m][2] * inv), (_Float16)(acc[m][3] * inv) };
        *(f16x4*)&O[(size_t)(b * TT + q) * DD + h * 64 + m * 16 + la * 4] = o;
    }
}

extern "C" void kernel_launch(void* const* d_in, const int* in_sizes, int n_in,
                              void* d_out, int out_size, void* d_ws, size_t ws_size,
                              hipStream_t stream) {
    const float* x    = (const float*)d_in[0];
    const float* W1q  = (const float*)d_in[1];
    const float* W2q  = (const float*)d_in[2];
    const float* W1k  = (const float*)d_in[3];
    const float* W2k  = (const float*)d_in[4];
    const float* Wv   = (const float*)d_in[5];
    const float* bv   = (const float*)d_in[6];
    const float* Wout = (const float*)d_in[7];
    const float* bout = (const float*)d_in[8];
    float* out = (float*)d_out;

    char* wsb = (char*)d_ws;
    _Float16* xb      = (_Float16*)(wsb);                  //  8,388,608
    _Float16* AObf    = (_Float16*)(wsb);                  //  aliases xb (dead after qkv GEMM)
    _Float16* Wqkvb   = (_Float16*)(wsb + 8388608);        //  2,621,440
    _Float16* Woutb   = (_Float16*)(wsb + 11010048);       //  2,097,152
    float*    biasqkv = (float*)   (wsb + 13107200);       //      5,120
    float*    Cqkv    = (float*)   (wsb + 13112320);       // 20,971,520
    _Float16* Lqh     = (_Float16*)(wsb + 34083840);       //  2,097,152
    _Float16* JKf     = (_Float16*)(wsb + 36180992);       //  2,097,152
    _Float16* Vf      = (_Float16*)(wsb + 38278144);       //  8,388,608  (end ~44.5 MB)

    // 1. fp32 -> f16 pack
    convert_kernel<<<dim3(3201), 256, 0, stream>>>(
        x, W1q, W2q, W1k, W2k, Wv, Wout, bv, xb, Wqkvb, Woutb, biasqkv);
    // 2. fused qkv projection: Cqkv = xb @ Wqkvb^T + biasqkv   [4096,1280]
    gemm_f16_mfma<<<dim3(BT / 128, VD / 128), 256, 0, stream>>>(
        xb, Wqkvb, biasqkv, Cqkv, VD, DD);
    // 3. Plucker lines -> Lqh + JKf (fragment order)
    exterior_kernel<<<dim3(BT * HH / 256), 256, 0, stream>>>(Cqkv, Lqh, JKf);
    // 4. V -> PV-fragment order f16
    vtrans_kernel<<<dim3(TT / 64, BB * HH), 256, 0, stream>>>(Cqkv, Vf);
    // 5. causal flash attention (barrier-free, per-wave staging)
    flash_mfma_kernel<<<dim3(TT / 64, BB * HH), 256, 0, stream>>>(Lqh, JKf, Vf, AObf);
    // 6. output projection
    gemm_f16_mfma<<<dim3(BT / 128, DD / 128), 256, 0, stream>>>(
        AObf, Woutb, bout, out, DD, DD);
}